// Round 8
// baseline (101.234 us; speedup 1.0000x reference)
//
#include <hip/hip_runtime.h>
#include <stdint.h>

#define BATCH 1024
#define DIM 768

typedef unsigned long long u64;
typedef __attribute__((ext_vector_type(8))) short short8;  // 8 bf16 = 4 VGPRs
typedef __attribute__((ext_vector_type(4))) float f32x4;

// Workspace layout (bytes):
//   [0]      float acc                 (zeroed by prep block 0)
//   [8]      int   rowdonecnt          (zeroed by prep block 0)
//   [4096]   int   rowcnt[1024]        (4 KB, zeroed by prep block 0)
//   [12288]  float pmax[1024*4]        (16 KB) per-row per-chunk max
//   [28672]  float psum[1024*4]        (16 KB) per-row per-chunk sumexp
//   [45056]  float lval[1024]          (4 KB)  exact fp32 label logit (prep)
//   [49152]  ushort txtB[1024*768]     (1.5 MB) bf16, MFMA B-frag order
// B-frag order: off(col,k) = ((k>>5)*64 + (col>>4))*512 + ((k>>3)&3)*128
//                            + (col&15)*8 + (k&7)
#define WS_ACC      0
#define WS_RDC      8
#define WS_ROWCNT 4096
#define WS_PMAX  12288
#define WS_PSUM  28672
#define WS_LVAL  45056
#define WS_TXTB  49152

__device__ __forceinline__ unsigned short to_bf16(float x) {
    unsigned int u = __float_as_uint(x);
    return (unsigned short)((u + 0x7FFFu + ((u >> 16) & 1u)) >> 16);  // RNE
}

__device__ __forceinline__ float atomic_read_f32(float* p) {
    // coherent-point RMW read (writes back same bits)
    unsigned int v = atomicOr((unsigned int*)p, 0u);
    return __uint_as_float(v);
}

// ---------------------------------------------------------------------------
// K1: txt fp32 -> bf16 B-frag order + per-row labels & exact fp32 label
// logit + zero acc/rowdonecnt/rowcnt. 256 blocks x 256 threads.
// Wave w owns label-row j = b*4 + w (1024 waves total — same parallelism as
// before, now overlapped with the convert and off gemm's critical path).
// ---------------------------------------------------------------------------
__global__ __launch_bounds__(256) void prep_kernel(
        const float* __restrict__ img, const float* __restrict__ txt,
        const float* __restrict__ scale_p,
        unsigned short* __restrict__ txtB, float* __restrict__ lval,
        float* __restrict__ acc, int* __restrict__ rowdonecnt,
        int* __restrict__ rowcnt) {
    const int wave = threadIdx.x >> 6;
    const int lane = threadIdx.x & 63;

    if (blockIdx.x == 0) {
        rowcnt[threadIdx.x * 4 + 0] = 0;
        rowcnt[threadIdx.x * 4 + 1] = 0;
        rowcnt[threadIdx.x * 4 + 2] = 0;
        rowcnt[threadIdx.x * 4 + 3] = 0;
        if (threadIdx.x == 0) { *acc = 0.0f; *rowdonecnt = 0; }
    }

    // txt fp32 -> bf16 B-frag order (R1/R7-proven, bit-exact)
    for (int i = wave; i < 6; i += 4) {
        const int G  = blockIdx.x * 6 + i;
        const int tt = G / 24;        // col-tile 0..63
        const int g  = G - tt * 24;   // k-group 0..23
        const int col = tt * 16 + (lane & 15);
        const int k0  = g * 32 + (lane >> 4) * 8;
        const float4 va = *(const float4*)(txt + (size_t)col * DIM + k0);
        const float4 vb = *(const float4*)(txt + (size_t)col * DIM + k0 + 4);
        short8 hv = {(short)to_bf16(va.x), (short)to_bf16(va.y),
                     (short)to_bf16(va.z), (short)to_bf16(va.w),
                     (short)to_bf16(vb.x), (short)to_bf16(vb.y),
                     (short)to_bf16(vb.z), (short)to_bf16(vb.w)};
        *(short8*)(txtB + (size_t)(g * 64 + tt) * 512 + lane * 8) = hv;
    }

    // labels: wave w owns row j = b*4 + w. Filter: float2 signature (float
    // compares -> can never exclude a true float== match); decide: exact
    // float== verify. (R3-R7 proven, absmax 0.0)
    {
        const int j = blockIdx.x * 4 + wave;
        const float2 sj = *(const float2*)(img + (size_t)j * DIM);
        int lo = -1;
        int label = j;
        for (;;) {
            int cand = BATCH;
#pragma unroll
            for (int it = 0; it < 16; ++it) {
                const int i = lane + it * 64;          // always < 1024
                const float2 si = *(const float2*)(img + (size_t)i * DIM);
                if (i < j && i > lo && si.x == sj.x && si.y == sj.y)
                    cand = min(cand, i);
            }
#pragma unroll
            for (int s = 32; s; s >>= 1) cand = min(cand, __shfl_xor(cand, s, 64));
            if (cand >= j) break;                      // no candidate -> label = j
            const float4* rpm = (const float4*)(img + (size_t)cand * DIM);
            const float4* rpj = (const float4*)(img + (size_t)j * DIM);
            bool eq = true;
#pragma unroll
            for (int cc = 0; cc < 3; ++cc) {
                float4 vm = rpm[cc * 64 + lane];
                float4 vj = rpj[cc * 64 + lane];
                eq = eq && (vm.x == vj.x) && (vm.y == vj.y) &&
                     (vm.z == vj.z) && (vm.w == vj.w);
            }
            if (__all(eq)) { label = cand; break; }
            lo = cand;                                 // false positive: rescan above
        }

        // exact fp32 label logit: scale * dot(img[j], txt[label]) (unchanged)
        const float4* aj = (const float4*)(img + (size_t)j * DIM);
        const float4* bl = (const float4*)(txt + (size_t)label * DIM);
        float s = 0.0f;
#pragma unroll
        for (int cc = 0; cc < 3; ++cc) {
            const float4 va = aj[cc * 64 + lane];
            const float4 vb = bl[cc * 64 + lane];
            s += va.x * vb.x + va.y * vb.y + va.z * vb.z + va.w * vb.w;
        }
#pragma unroll
        for (int m = 32; m; m >>= 1) s += __shfl_xor(s, m, 64);
        if (lane == 0) atomicExch(&lval[j], scale_p[0] * s);
    }
}

// ---------------------------------------------------------------------------
// K2: MFMA GEMM + softmax partials + DISTRIBUTED per-row finalize.
// 256 blocks x 1024 thr. Block = 16 rows x 256 cols. Kernel ends at the
// last publish — no label phase, no block-wide tail, no barriers after the
// partials, no spin loops.
//
// Publisher (wave w lane 0, row = r0+w, chunk c): exch pmax, exch psum,
// consume returns via asm sink (forces vmcnt drain -> exchanges complete at
// the coherent point), then atomicAdd(rowcnt[row],1). The 4th publisher
// (old==3) finalizes the row: RMW-reads the 8 partials (coherent point),
// plain-reads lval (cross-kernel boundary, R0-proven), atomicAdd(acc,loss),
// sink, atomicAdd(rowdonecnt,1); the 1024th reads the total via
// atomicAdd(acc,0) (RMW serialization => all adds landed) and writes out.
// ---------------------------------------------------------------------------
__global__ __launch_bounds__(1024) void gemm_fused(
        const float* __restrict__ img, const float* __restrict__ scale_p,
        const unsigned short* __restrict__ txtB,
        float* __restrict__ pmax, float* __restrict__ psum,
        float* __restrict__ lval, float* __restrict__ acc,
        int* __restrict__ rowdonecnt, int* __restrict__ rowcnt,
        float* __restrict__ out) {
    __shared__ unsigned short Ahi[16 * DIM];   // 24 KB, A-frag order
    __shared__ float logitsS[16 * 260];        // 16.6 KB (+4 pad vs bank stride)

    const int tid  = threadIdx.x;
    const int wave = tid >> 6;
    const int lane = tid & 63;
    const int quad = lane >> 4;
    const int l15  = lane & 15;
    const int r0    = (blockIdx.x >> 2) * 16;
    const int chunk = blockIdx.x & 3;

    // stage A: wave w converts img row r0+w into frag order
    {
        const float* ir = img + (size_t)(r0 + wave) * DIM;
#pragma unroll
        for (int j = 0; j < 12; ++j) {
            const int k = lane + j * 64;
            Ahi[((k >> 3) * 16 + wave) * 8 + (k & 7)] = to_bf16(ir[k]);
        }
    }
    __syncthreads();

    // k-loop: wave's col-tile t, one MFMA per 32-k step; B-frags contiguous
    const int t = chunk * 16 + wave;
    const int foff = quad * 128 + l15 * 8;
    f32x4 a4 = {0.f, 0.f, 0.f, 0.f};
#pragma unroll
    for (int kk = 0; kk < 24; ++kk) {
        const short8 a = *(const short8*)&Ahi[kk * 512 + foff];
        const short8 b = *(const short8*)(txtB + (size_t)(kk * 64 + t) * 512 + foff);
        a4 = __builtin_amdgcn_mfma_f32_16x16x32_bf16(a, b, a4, 0, 0, 0);
    }

    // C layout: col = l15, row = quad*4 + r  [verified, absmax 0.0]
    const float scale = scale_p[0];
#pragma unroll
    for (int r = 0; r < 4; ++r)
        logitsS[(quad * 4 + r) * 260 + wave * 16 + l15] = scale * a4[r];
    __syncthreads();

    // per-row partials: wave w = row r0+w; 4 floats/lane over 256 cols
    const float4 f = *(const float4*)&logitsS[wave * 260 + lane * 4];
    float mx = fmaxf(fmaxf(f.x, f.y), fmaxf(f.z, f.w));
#pragma unroll
    for (int s = 32; s; s >>= 1) mx = fmaxf(mx, __shfl_xor(mx, s, 64));
    float sum = __expf(f.x - mx) + __expf(f.y - mx) +
                __expf(f.z - mx) + __expf(f.w - mx);
#pragma unroll
    for (int s = 32; s; s >>= 1) sum += __shfl_xor(sum, s, 64);

    if (lane == 0) {
        const int row = r0 + wave;
        const float o1 = atomicExch(&pmax[row * 4 + chunk], mx);
        const float o2 = atomicExch(&psum[row * 4 + chunk], sum);
        asm volatile("" :: "v"(o1), "v"(o2));   // drain: exchanges complete
        const int old = atomicAdd(&rowcnt[row], 1);
        if (old == 3) {
            // finalize row: all 4 chunk partials are at the coherent point
            float pm[4], ps[4];
#pragma unroll
            for (int c = 0; c < 4; ++c) {
                pm[c] = atomic_read_f32(&pmax[row * 4 + c]);
                ps[c] = atomic_read_f32(&psum[row * 4 + c]);
            }
            const float lv = lval[row];   // prep-written, kernel-boundary safe
            const float gmax = fmaxf(fmaxf(pm[0], pm[1]), fmaxf(pm[2], pm[3]));
            const float ss = ps[0] * __expf(pm[0] - gmax)
                           + ps[1] * __expf(pm[1] - gmax)
                           + ps[2] * __expf(pm[2] - gmax)
                           + ps[3] * __expf(pm[3] - gmax);
            const float loss = gmax + __logf(ss) - lv;
            const float ao = atomicAdd(acc, loss);
            asm volatile("" :: "v"(ao));        // drain: acc add complete
            const int dold = atomicAdd(rowdonecnt, 1);
            if (dold == (int)BATCH - 1) {
                const float tot = atomicAdd(acc, 0.0f);  // all adds landed
                out[0] = tot * (1.0f / BATCH);
            }
        }
    }
}

extern "C" void kernel_launch(void* const* d_in, const int* in_sizes, int n_in,
                              void* d_out, int out_size, void* d_ws, size_t ws_size,
                              hipStream_t stream) {
    const float* img   = (const float*)d_in[0];
    const float* txt   = (const float*)d_in[1];
    const float* scale = (const float*)d_in[2];
    float* out = (float*)d_out;
    char* ws = (char*)d_ws;

    float* acc        = (float*)(ws + WS_ACC);
    int*   rowdonecnt = (int*)(ws + WS_RDC);
    int*   rowcnt     = (int*)(ws + WS_ROWCNT);
    float* pmax       = (float*)(ws + WS_PMAX);
    float* psum       = (float*)(ws + WS_PSUM);
    float* lval       = (float*)(ws + WS_LVAL);
    unsigned short* txtB = (unsigned short*)(ws + WS_TXTB);

    prep_kernel<<<256, 256, 0, stream>>>(img, txt, scale, txtB, lval,
                                         acc, rowdonecnt, rowcnt);
    gemm_fused<<<256, 1024, 0, stream>>>(img, scale, txtB,
                                         pmax, psum, lval, acc,
                                         rowdonecnt, rowcnt, out);
}

// Round 9
// 79.972 us; speedup vs baseline: 1.2659x; 1.2659x over previous
//
#include <hip/hip_runtime.h>
#include <stdint.h>

#define BATCH 1024
#define DIM 768

typedef unsigned long long u64;
typedef __attribute__((ext_vector_type(8))) short short8;   // 8 bf16 = 4 VGPRs
typedef __attribute__((ext_vector_type(4))) short short4v;  // 4 bf16 = 2 VGPRs
typedef __attribute__((ext_vector_type(4))) float f32x4;

// Workspace layout (bytes):
//   [0]      int   tailcnt             (zeroed by prep block 0)
//   [4096]   float pmax[1024*4]        (16 KB) per-row per-chunk max
//   [20480]  float psum[1024*4]        (16 KB) per-row per-chunk sumexp
//   [36864]  float lval[1024]          (4 KB)  exact fp32 label logit per row
//   [49152]  ushort txtB[1024*768]     (1.5 MB) bf16, MFMA B-frag order
// B-frag order: off(col,k) = ((k>>5)*64 + (col>>4))*512 + ((k>>3)&3)*128
//                            + (col&15)*8 + (k&7)
#define WS_TAIL     0
#define WS_PMAX  4096
#define WS_PSUM 20480
#define WS_LVAL 36864
#define WS_TXTB 49152

__device__ __forceinline__ unsigned short to_bf16(float x) {
    unsigned int u = __float_as_uint(x);
    return (unsigned short)((u + 0x7FFFu + ((u >> 16) & 1u)) >> 16);  // RNE
}

// ---------------------------------------------------------------------------
// K1: txt fp32 -> bf16 B-frag order + zero tailcnt. 256 blocks x 256 threads.
// (R7-proven, unchanged.)
// ---------------------------------------------------------------------------
__global__ __launch_bounds__(256) void prep_kernel(
        const float* __restrict__ txt, int* __restrict__ tailcnt,
        unsigned short* __restrict__ txtB) {
    if (blockIdx.x == 0 && threadIdx.x == 0) { *tailcnt = 0; }
    const int wave = threadIdx.x >> 6;
    const int lane = threadIdx.x & 63;

    for (int i = wave; i < 6; i += 4) {
        const int G  = blockIdx.x * 6 + i;
        const int tt = G / 24;        // col-tile 0..63
        const int g  = G - tt * 24;   // k-group 0..23
        const int col = tt * 16 + (lane & 15);
        const int k0  = g * 32 + (lane >> 4) * 8;
        const float4 va = *(const float4*)(txt + (size_t)col * DIM + k0);
        const float4 vb = *(const float4*)(txt + (size_t)col * DIM + k0 + 4);
        short8 hv = {(short)to_bf16(va.x), (short)to_bf16(va.y),
                     (short)to_bf16(va.z), (short)to_bf16(va.w),
                     (short)to_bf16(vb.x), (short)to_bf16(vb.y),
                     (short)to_bf16(vb.z), (short)to_bf16(vb.w)};
        *(short8*)(txtB + (size_t)(g * 64 + tt) * 512 + lane * 8) = hv;
    }
}

// ---------------------------------------------------------------------------
// K2: MFMA GEMM + softmax partials + labels + label logit + last-block
// combine. 256 blocks x 1024 thr (1 block/CU -> VGPR growth to <=128 is
// occupancy-free). R7-proven body with two latency micro-opts:
//   - float4 A-staging (R5-verified bit-identical values/destinations)
//   - waves 0..3 prefetch their 16 float2 label signatures BEFORE the
//     k-loop (scan runs on registers after the partials; the scan's L2
//     round trip overlaps the whole k-loop). False-positive rescan path
//     reloads from memory (identical values -> identical result).
// No release threadfence (R7-verified ordering: device-scope atomicExch
// data publishes complete at the coherent point before the __syncthreads
// vmcnt(0) drain lets tid0 issue the tailcnt RMW). No spin loops.
// ---------------------------------------------------------------------------
__global__ __launch_bounds__(1024) void gemm_fused(
        const float* __restrict__ img, const float* __restrict__ txt,
        const float* __restrict__ scale_p, const unsigned short* __restrict__ txtB,
        float* __restrict__ pmax, float* __restrict__ psum,
        float* __restrict__ lval, int* __restrict__ tailcnt,
        float* __restrict__ out) {
    __shared__ unsigned short Ahi[16 * DIM];   // 24 KB, A-frag order
    __shared__ float logitsS[16 * 260];        // 16.6 KB (+4 pad vs bank stride)
    __shared__ int isLast;
    __shared__ float part[16];

    const int tid  = threadIdx.x;
    const int wave = tid >> 6;
    const int lane = tid & 63;
    const int quad = lane >> 4;
    const int l15  = lane & 15;
    const int r0    = (blockIdx.x >> 2) * 16;
    const int chunk = blockIdx.x & 3;

    // stage A: wave w converts img row r0+w into frag order (float4 loads,
    // bit-identical values/destinations to the scalar version — R5-verified)
    {
        const float* ir = img + (size_t)(r0 + wave) * DIM;
#pragma unroll
        for (int j = 0; j < 3; ++j) {
            const int k0 = lane * 4 + j * 256;
            const float4 v = *(const float4*)(ir + k0);
            short4v h = {(short)to_bf16(v.x), (short)to_bf16(v.y),
                         (short)to_bf16(v.z), (short)to_bf16(v.w)};
            *(short4v*)&Ahi[((k0 >> 3) * 16 + wave) * 8 + (k0 & 7)] = h;
        }
    }

    // label-signature prefetch (waves 0..3): issue the 16 float2 loads now;
    // they complete during the k-loop. +32 VGPR, free at 1 block/CU.
    const int jrow = r0 + chunk * 4 + wave;   // valid for wave<4
    float2 sig[16];
    if (wave < 4) {
#pragma unroll
        for (int it = 0; it < 16; ++it)
            sig[it] = *(const float2*)(img + (size_t)(lane + it * 64) * DIM);
    }
    __syncthreads();

    // k-loop: wave's global col-tile t, one MFMA per 32-k step; B-frags are
    // contiguous 1 KB runs in txtB (L2-resident) — no k-loop barriers.
    const int t = chunk * 16 + wave;
    const int foff = quad * 128 + l15 * 8;
    f32x4 acc = {0.f, 0.f, 0.f, 0.f};
#pragma unroll
    for (int kk = 0; kk < 24; ++kk) {
        const short8 a = *(const short8*)&Ahi[kk * 512 + foff];
        const short8 b = *(const short8*)(txtB + (size_t)(kk * 64 + t) * 512 + foff);
        acc = __builtin_amdgcn_mfma_f32_16x16x32_bf16(a, b, acc, 0, 0, 0);
    }

    // C layout: col = l15, row = quad*4 + r  [verified, absmax 0.0]
    const float scale = scale_p[0];
#pragma unroll
    for (int r = 0; r < 4; ++r)
        logitsS[(quad * 4 + r) * 260 + wave * 16 + l15] = scale * acc[r];
    __syncthreads();

    // per-row partials: wave w = row r0+w; 4 floats/lane over 256 cols
    {
        const float4 f = *(const float4*)&logitsS[wave * 260 + lane * 4];
        float mx = fmaxf(fmaxf(f.x, f.y), fmaxf(f.z, f.w));
#pragma unroll
        for (int s = 32; s; s >>= 1) mx = fmaxf(mx, __shfl_xor(mx, s, 64));
        float sum = __expf(f.x - mx) + __expf(f.y - mx) +
                    __expf(f.z - mx) + __expf(f.w - mx);
#pragma unroll
        for (int s = 32; s; s >>= 1) sum += __shfl_xor(sum, s, 64);
        if (lane == 0) {
            atomicExch(&pmax[(r0 + wave) * 4 + chunk], mx);
            atomicExch(&psum[(r0 + wave) * 4 + chunk], sum);
        }
    }

    // labels: waves 0..3 handle row j = jrow. First pass uses the
    // prefetched signatures (registers); fallback rescan (hash-improbable
    // float2 collision) reloads from memory — identical values.
    if (wave < 4) {
        const int j = jrow;
        const float2 sj = *(const float2*)(img + (size_t)j * DIM);
        int label = j;
        int cand = BATCH;
#pragma unroll
        for (int it = 0; it < 16; ++it) {
            const int i = lane + it * 64;
            if (i < j && sig[it].x == sj.x && sig[it].y == sj.y)
                cand = min(cand, i);
        }
#pragma unroll
        for (int s = 32; s; s >>= 1) cand = min(cand, __shfl_xor(cand, s, 64));
        int lo = -1;
        while (cand < j) {
            // exact verify rows cand vs j
            const float4* rpm = (const float4*)(img + (size_t)cand * DIM);
            const float4* rpj = (const float4*)(img + (size_t)j * DIM);
            bool eq = true;
#pragma unroll
            for (int cc = 0; cc < 3; ++cc) {
                float4 vm = rpm[cc * 64 + lane];
                float4 vj = rpj[cc * 64 + lane];
                eq = eq && (vm.x == vj.x) && (vm.y == vj.y) &&
                     (vm.z == vj.z) && (vm.w == vj.w);
            }
            if (__all(eq)) { label = cand; break; }
            lo = cand;                         // false positive: rescan above it
            cand = BATCH;
#pragma unroll
            for (int it = 0; it < 16; ++it) {
                const int i = lane + it * 64;
                const float2 si = *(const float2*)(img + (size_t)i * DIM);
                if (i < j && i > lo && si.x == sj.x && si.y == sj.y)
                    cand = min(cand, i);
            }
#pragma unroll
            for (int s = 32; s; s >>= 1) cand = min(cand, __shfl_xor(cand, s, 64));
        }

        // exact fp32 label logit: scale * dot(img[j], txt[label])
        const float4* aj = (const float4*)(img + (size_t)j * DIM);
        const float4* bl = (const float4*)(txt + (size_t)label * DIM);
        float s = 0.0f;
#pragma unroll
        for (int cc = 0; cc < 3; ++cc) {
            const float4 va = aj[cc * 64 + lane];
            const float4 vb = bl[cc * 64 + lane];
            s += va.x * vb.x + va.y * vb.y + va.z * vb.z + va.w * vb.w;
        }
#pragma unroll
        for (int m = 32; m; m >>= 1) s += __shfl_xor(s, m, 64);
        if (lane == 0) atomicExch(&lval[j], scale * s);
    }

    // last-block tail (R7-verified, no release fence, no spins)
    __syncthreads();
    if (tid == 0)
        isLast = (atomicAdd(tailcnt, 1) == (int)gridDim.x - 1) ? 1 : 0;
    __syncthreads();
    if (!isLast) return;
    __threadfence();   // acquire: invalidate local caches before remote reads

    // thread t combines row t: lse from 4 chunk partials minus label logit
    {
        const float4 m4 = *(const float4*)&pmax[tid * 4];
        const float4 s4 = *(const float4*)&psum[tid * 4];
        const float lv = lval[tid];
        const float gmax = fmaxf(fmaxf(m4.x, m4.y), fmaxf(m4.z, m4.w));
        const float ss = s4.x * __expf(m4.x - gmax) + s4.y * __expf(m4.y - gmax)
                       + s4.z * __expf(m4.z - gmax) + s4.w * __expf(m4.w - gmax);
        float loss = gmax + __logf(ss) - lv;
#pragma unroll
        for (int m = 32; m; m >>= 1) loss += __shfl_xor(loss, m, 64);
        if (lane == 0) part[wave] = loss;
        __syncthreads();
        if (tid == 0) {
            float tot = 0.0f;
#pragma unroll
            for (int w = 0; w < 16; ++w) tot += part[w];
            out[0] = tot * (1.0f / BATCH);
        }
    }
}

extern "C" void kernel_launch(void* const* d_in, const int* in_sizes, int n_in,
                              void* d_out, int out_size, void* d_ws, size_t ws_size,
                              hipStream_t stream) {
    const float* img   = (const float*)d_in[0];
    const float* txt   = (const float*)d_in[1];
    const float* scale = (const float*)d_in[2];
    float* out = (float*)d_out;
    char* ws = (char*)d_ws;

    int*   tailcnt = (int*)(ws + WS_TAIL);
    float* pmax    = (float*)(ws + WS_PMAX);
    float* psum    = (float*)(ws + WS_PSUM);
    float* lval    = (float*)(ws + WS_LVAL);
    unsigned short* txtB = (unsigned short*)(ws + WS_TXTB);

    prep_kernel<<<256, 256, 0, stream>>>(txt, tailcnt, txtB);
    gemm_fused<<<256, 1024, 0, stream>>>(img, txt, scale, txtB,
                                         pmax, psum, lval, tailcnt, out);
}